// Round 1
// baseline (230.417 us; speedup 1.0000x reference)
//
#include <hip/hip_runtime.h>
#include <stdint.h>

// ---------------------------------------------------------------------------
// Cosine similarity: C[n][m] = <z_n/||z_n||, cm_m/||cm_m||>
// M=32768 rows z, Ncls=1001 rows cm, K=512, out fp32 [M][Ncls].
// Pass 1 (tiny): normalize cm rows -> bf16 bn [Npad=1024][512] in d_ws.
// Pass 2 (fused): GEMM C = bf16(z) * bn^T scaled by 1/||z_row||.
//   R1 changes vs previous version:
//   - XCD-chunked block swizzle: the 4 N-sibling blocks of each M-tile are
//     consecutive within one XCD -> A-tile fetched into that L2 once
//     (was: round-robin across 4 XCDs, A fetched ~2.1x from HBM).
//   - BK=32 full double-buffer (A and B LDS), ONE barrier per substep:
//     stage substep s+1 (B via global_load_lds, A via reg->bf16->ds_write)
//     before MFMA of substep s; each load gets a full substep in flight
//     before the barrier drain (was: issue->drain ~150 cycles).
//   Same LDS total (48.5 KB), same barrier count (16), 2 blocks/CU
//   (VGPR-capped: 64 arch + 64 acc).
// Workspace need: 1024*512*2 B = 1 MB.
// ---------------------------------------------------------------------------

typedef short short8 __attribute__((ext_vector_type(8)));
typedef float f32x16 __attribute__((ext_vector_type(16)));

#define KDIM 512
#define KSUB 32           // K per substep
#define NSUBSTEPS 16      // KDIM / KSUB

__device__ __forceinline__ unsigned short f2bf(float f) {
  uint32_t u = __float_as_uint(f);
  u += 0x7FFFu + ((u >> 16) & 1u);   // round-to-nearest-even
  return (unsigned short)(u >> 16);
}

__device__ __forceinline__ void gload_lds16(const unsigned short* g,
                                            unsigned short* l) {
  __builtin_amdgcn_global_load_lds(
      (const __attribute__((address_space(1))) void*)g,
      (__attribute__((address_space(3))) void*)l, 16, 0, 0);
}

// One wave per cm row; rows >= Ncls written as zeros (GEMM B-side pad).
__global__ __launch_bounds__(256) void normalize_cm_kernel(
    const float* __restrict__ cm, unsigned short* __restrict__ bn,
    int Ncls, int Npad) {
  int r = blockIdx.x * 4 + (threadIdx.x >> 6);
  int lane = threadIdx.x & 63;
  if (r >= Npad) return;
  unsigned short* dst = bn + (size_t)r * KDIM;
  if (r >= Ncls) {
    uint2 zv = make_uint2(0u, 0u);
    *(uint2*)(dst + lane * 4) = zv;
    *(uint2*)(dst + 256 + lane * 4) = zv;
    return;
  }
  const float4* s4 = (const float4*)(cm + (size_t)r * KDIM);
  float4 x0 = s4[lane];
  float4 x1 = s4[lane + 64];
  float s = x0.x * x0.x + x0.y * x0.y + x0.z * x0.z + x0.w * x0.w +
            x1.x * x1.x + x1.y * x1.y + x1.z * x1.z + x1.w * x1.w;
#pragma unroll
  for (int off = 32; off > 0; off >>= 1) s += __shfl_xor(s, off, 64);
  float scale = 1.0f / fmaxf(sqrtf(s), 1e-8f);

  union { unsigned short u[4]; uint2 v; } p0, p1;
  p0.u[0] = f2bf(x0.x * scale); p0.u[1] = f2bf(x0.y * scale);
  p0.u[2] = f2bf(x0.z * scale); p0.u[3] = f2bf(x0.w * scale);
  p1.u[0] = f2bf(x1.x * scale); p1.u[1] = f2bf(x1.y * scale);
  p1.u[2] = f2bf(x1.z * scale); p1.u[3] = f2bf(x1.w * scale);
  *(uint2*)(dst + lane * 4) = p0.v;
  *(uint2*)(dst + 256 + lane * 4) = p1.v;
}

// Convert 8 fp32 (2 float4) -> 8 bf16, accumulate ssq into rs, ds_write_b128.
#define STAGE_A(xa, xb, dst)                                                   \
  do {                                                                         \
    rs += (xa).x * (xa).x + (xa).y * (xa).y + (xa).z * (xa).z +                \
          (xa).w * (xa).w + (xb).x * (xb).x + (xb).y * (xb).y +                \
          (xb).z * (xb).z + (xb).w * (xb).w;                                   \
    union { unsigned short u[8]; uint4 v; } pk;                                \
    pk.u[0] = f2bf((xa).x); pk.u[1] = f2bf((xa).y);                            \
    pk.u[2] = f2bf((xa).z); pk.u[3] = f2bf((xa).w);                            \
    pk.u[4] = f2bf((xb).x); pk.u[5] = f2bf((xb).y);                            \
    pk.u[6] = f2bf((xb).z); pk.u[7] = f2bf((xb).w);                            \
    *(uint4*)(dst) = pk.v;                                                     \
  } while (0)

// 8 MFMA over buffer parity p (2 k16 slices of the 32-col substep tile).
#define MFMA_PHASE(p)                                                          \
  do {                                                                         \
    _Pragma("unroll")                                                          \
    for (int ks = 0; ks < 2; ++ks) {                                           \
      const int uo = (((ks << 1) | kh) ^ fsw) * 8;                             \
      short8 a0 = *(const short8*)&As[p][(wm + fm) * KSUB + uo];               \
      short8 a1 = *(const short8*)&As[p][(wm + 32 + fm) * KSUB + uo];          \
      short8 b0 = *(const short8*)&Bs[p][(wn + fm) * KSUB + uo];               \
      short8 b1 = *(const short8*)&Bs[p][(wn + 32 + fm) * KSUB + uo];          \
      acc[0][0] = __builtin_amdgcn_mfma_f32_32x32x16_bf16(a0, b0, acc[0][0], 0, 0, 0); \
      acc[0][1] = __builtin_amdgcn_mfma_f32_32x32x16_bf16(a0, b1, acc[0][1], 0, 0, 0); \
      acc[1][0] = __builtin_amdgcn_mfma_f32_32x32x16_bf16(a1, b0, acc[1][0], 0, 0, 0); \
      acc[1][1] = __builtin_amdgcn_mfma_f32_32x32x16_bf16(a1, b1, acc[1][1], 0, 0, 0); \
    }                                                                          \
  } while (0)

// Fused: C = bf16(Z) * B^T, rows scaled by 1/max(||Z_row||, 1e-8).
// Z: [M][512] fp32, B: [Npad][512] bf16 bits, C: [M][Ncls] f32.
__global__ __launch_bounds__(512, 4) void gemm_fused_kernel(
    const float* __restrict__ Z,
    const unsigned short* __restrict__ B,
    float* __restrict__ C, int M, int Ncls) {
  // Double-buffered substep tiles, rows of 32 bf16 (64 B), 4-slot XOR swizzle.
  __shared__ unsigned short As[2][128 * KSUB];   // 2 x 8 KB
  __shared__ unsigned short Bs[2][256 * KSUB];   // 2 x 16 KB
  __shared__ float ns[128];                      // row ||z||^2

  const int tid = threadIdx.x;
  const int wave = tid >> 6;
  const int lane = tid & 63;

  // XCD-chunked bijective swizzle (nwg % 8 == 0): XCD k gets wg's
  // [k*cpx, (k+1)*cpx); within an XCD the 4 N-siblings of an M-tile are
  // adjacent -> concurrent -> A-tile hits that XCD's L2.
  const int nwg = gridDim.x;
  const int cpx = nwg >> 3;
  const int bid = blockIdx.x;
  const int wg = (bid & 7) * cpx + (bid >> 3);
  const int m0 = (wg >> 2) * 128;
  const int n0 = (wg & 3) * 256;

  const int wm = (wave & 1) * 64;   // wave's M offset
  const int wn = (wave >> 1) * 64;  // wave's N offset (0..192)

  // ---- A staging map: thread t -> row t>>2, LDS unit t&3; source unit is
  // XOR-pre-swizzled so LDS[r][u'] holds source unit u' ^ (r&3).
  const int rA = tid >> 2;                 // 0..127
  const int gA = tid & 3;                  // LDS unit slot
  const int uA = gA ^ (rA & 3);            // source col-group
  const float* Ag = Z + (size_t)(m0 + rA) * KDIM + uA * 8;
  unsigned short* Aw0 = &As[0][rA * KSUB + gA * 8];
  unsigned short* Aw1 = &As[1][rA * KSUB + gA * 8];

  // ---- B staging map: per wave 2 chunks of 16 rows x 32 cols (1 KB each);
  // global_load_lds writes linearly (base + lane*16); source address carries
  // the same XOR swizzle so the read side matches A's.
  const int l2 = lane >> 2;                // row within chunk 0..15
  const int uB = (lane & 3) ^ (l2 & 3);    // source col-group
  const unsigned short* Bg[2];
  unsigned short* Bl0[2];
  unsigned short* Bl1[2];
#pragma unroll
  for (int cc = 0; cc < 2; ++cc) {
    int c = wave * 2 + cc;                 // chunk 0..15
    Bg[cc] = B + (size_t)(n0 + c * 16 + l2) * KDIM + uB * 8;
    Bl0[cc] = &Bs[0][c * 16 * KSUB];       // wave-uniform LDS base
    Bl1[cc] = &Bs[1][c * 16 * KSUB];
  }

  const int fm = lane & 31;        // fragment row (A: m, B: n)
  const int kh = lane >> 5;        // k-half
  const int fsw = fm & 3;          // read-side swizzle phase

  f32x16 acc[2][2] = {};
  float rs = 0.0f;                 // this thread's partial row ssq

  // ---- prologue: stage substep 0 into parity 0, prefetch A(1) regs.
  float4 p0a = *(const float4*)(Ag);
  float4 p0b = *(const float4*)(Ag + 4);
#pragma unroll
  for (int cc = 0; cc < 2; ++cc) gload_lds16(Bg[cc], Bl0[cc]);
  STAGE_A(p0a, p0b, Aw0);
  float4 p1a = *(const float4*)(Ag + KSUB);
  float4 p1b = *(const float4*)(Ag + KSUB + 4);
  __syncthreads();

#pragma unroll
  for (int it = 0; it < 8; ++it) {
    // ---- substep s = 2*it (compute parity 0; stage s+1 into parity 1)
    {
      const int s1 = 2 * it + 1;
#pragma unroll
      for (int cc = 0; cc < 2; ++cc)
        gload_lds16(Bg[cc] + s1 * KSUB, Bl1[cc]);
      if (it < 7) {                         // prefetch A(s+2) into p0
        p0a = *(const float4*)(Ag + (2 * it + 2) * KSUB);
        p0b = *(const float4*)(Ag + (2 * it + 2) * KSUB + 4);
      }
      STAGE_A(p1a, p1b, Aw1);               // A(s+1) from p1
      MFMA_PHASE(0);
      __syncthreads();
    }
    // ---- substep s = 2*it+1 (compute parity 1; stage s+1 into parity 0)
    {
      if (it < 7) {
        const int s1 = 2 * it + 2;
#pragma unroll
        for (int cc = 0; cc < 2; ++cc)
          gload_lds16(Bg[cc] + s1 * KSUB, Bl0[cc]);
        p1a = *(const float4*)(Ag + (2 * it + 3) * KSUB);   // A(s+2)
        p1b = *(const float4*)(Ag + (2 * it + 3) * KSUB + 4);
        STAGE_A(p0a, p0b, Aw0);             // A(s+1) from p0
      }
      MFMA_PHASE(1);
      if (it < 7) __syncthreads();
    }
  }

  // Finish row norms: 4 threads share each row (disjoint col-groups).
#pragma unroll
  for (int off = 1; off < 4; off <<= 1) rs += __shfl_xor(rs, off, 64);
  if ((lane & 3) == 0) ns[rA] = rs;
  __syncthreads();

  // Epilogue: C = acc * 1/max(||z_row||, eps).
  // C/D layout (32x32): col = lane&31, row = (r&3) + 8*(r>>2) + 4*(lane>>5).
  const int cn = lane & 31;
  const int ch4 = kh * 4;
#pragma unroll
  for (int mi = 0; mi < 2; ++mi) {
    float rn[16];
#pragma unroll
    for (int q = 0; q < 4; ++q) {
      float4 n4 = *(const float4*)&ns[wm + mi * 32 + q * 8 + ch4];
      rn[q * 4 + 0] = 1.0f / fmaxf(sqrtf(n4.x), 1e-8f);
      rn[q * 4 + 1] = 1.0f / fmaxf(sqrtf(n4.y), 1e-8f);
      rn[q * 4 + 2] = 1.0f / fmaxf(sqrtf(n4.z), 1e-8f);
      rn[q * 4 + 3] = 1.0f / fmaxf(sqrtf(n4.w), 1e-8f);
    }
#pragma unroll
    for (int ni = 0; ni < 2; ++ni) {
      int n = n0 + wn + ni * 32 + cn;
      if (n < Ncls) {
        size_t base = (size_t)(m0 + wm + mi * 32 + ch4) * (size_t)Ncls + n;
#pragma unroll
        for (int r = 0; r < 16; ++r) {
          int row = (r & 3) + 8 * (r >> 2);
          C[base + (size_t)row * Ncls] = acc[mi][ni][r] * rn[r];
        }
      }
    }
  }
}

extern "C" void kernel_launch(void* const* d_in, const int* in_sizes, int n_in,
                              void* d_out, int out_size, void* d_ws, size_t ws_size,
                              hipStream_t stream) {
  const float* z  = (const float*)d_in[0];
  const float* cm = (const float*)d_in[1];
  float* out = (float*)d_out;

  const int M    = in_sizes[0] / KDIM;                 // 32768
  const int Ncls = in_sizes[1] / KDIM;                 // 1001
  const int Npad = ((Ncls + 255) / 256) * 256;         // 1024

  unsigned short* bn = (unsigned short*)d_ws;          // 1 MB

  normalize_cm_kernel<<<Npad / 4, 256, 0, stream>>>(cm, bn, Ncls, Npad);

  // 1-D grid, XCD swizzle done in-kernel: (M/128) M-tiles x (Npad/256) N-tiles
  const int nwg = (M / 128) * (Npad / 256);            // 1024, % 8 == 0
  gemm_fused_kernel<<<dim3(nwg), 512, 0, stream>>>(z, bn, out, M, Ncls);
}

// Round 3
// 228.267 us; speedup vs baseline: 1.0094x; 1.0094x over previous
//
#include <hip/hip_runtime.h>
#include <stdint.h>

// ---------------------------------------------------------------------------
// Cosine similarity: C[n][m] = <z_n/||z_n||, cm_m/||cm_m||>
// M=32768 rows z, Ncls=1001 rows cm, K=512, out fp32 [M][Ncls].
// Pass 1 (tiny): normalize cm rows -> bf16 bn [Npad=1024][512] in d_ws.
// Pass 2 (fused): GEMM C = bf16(z) * bn^T scaled by 1/||z_row||.
//   R3 = R2 resubmit (R2 hit container-infra failure) with LDS hardened to
//   exactly 64 KB: the 512 B norm buffer now aliases As[0] (dead after the
//   K-loop; all As[0] reads complete at the s=14 barrier).
//   R2 changes vs R1 (unchanged here):
//   - Swizzle phase fixed: (row>>1)&3 instead of row&3. At 64 B rows,
//     bank = 16*(row&1) + 4*u; old phase gave lanes fm/fm+4 the same
//     (parity,u) -> 2-way conflict per 8-lane b128 group (12.6M conflict
//     cycles). New phase enumerates all 8 (parity,u) combos per group ->
//     conflict-free fragment reads.
//   - Counted-vmcnt pipeline (T3+T4): B triple-buffered, prefetched 2
//     substeps ahead; barriers are raw s_barrier + s_waitcnt vmcnt(4)
//     (never 0 in steady state) so B loads get ~2 substeps of cover.
//     A stays: global->reg (distance 2) -> f2bf -> ds_write (distance 1);
//     reg consumption is compiler-counted so it composes with manual vmcnt.
//   - s_setprio(1) around the MFMA cluster (T5).
//   LDS: Bs 3x16 KB + As 2x8 KB = 64 KB -> 2 blocks/CU.
// Workspace need: 1024*512*2 B = 1 MB.
// ---------------------------------------------------------------------------

typedef short short8 __attribute__((ext_vector_type(8)));
typedef float f32x16 __attribute__((ext_vector_type(16)));

#define KDIM 512
#define KSUB 32           // K per substep
#define NSUB 16           // KDIM / KSUB

__device__ __forceinline__ unsigned short f2bf(float f) {
  uint32_t u = __float_as_uint(f);
  u += 0x7FFFu + ((u >> 16) & 1u);   // round-to-nearest-even
  return (unsigned short)(u >> 16);
}

__device__ __forceinline__ void gload_lds16(const unsigned short* g,
                                            unsigned short* l) {
  __builtin_amdgcn_global_load_lds(
      (const __attribute__((address_space(1))) void*)g,
      (__attribute__((address_space(3))) void*)l, 16, 0, 0);
}

// One wave per cm row; rows >= Ncls written as zeros (GEMM B-side pad).
__global__ __launch_bounds__(256) void normalize_cm_kernel(
    const float* __restrict__ cm, unsigned short* __restrict__ bn,
    int Ncls, int Npad) {
  int r = blockIdx.x * 4 + (threadIdx.x >> 6);
  int lane = threadIdx.x & 63;
  if (r >= Npad) return;
  unsigned short* dst = bn + (size_t)r * KDIM;
  if (r >= Ncls) {
    uint2 zv = make_uint2(0u, 0u);
    *(uint2*)(dst + lane * 4) = zv;
    *(uint2*)(dst + 256 + lane * 4) = zv;
    return;
  }
  const float4* s4 = (const float4*)(cm + (size_t)r * KDIM);
  float4 x0 = s4[lane];
  float4 x1 = s4[lane + 64];
  float s = x0.x * x0.x + x0.y * x0.y + x0.z * x0.z + x0.w * x0.w +
            x1.x * x1.x + x1.y * x1.y + x1.z * x1.z + x1.w * x1.w;
#pragma unroll
  for (int off = 32; off > 0; off >>= 1) s += __shfl_xor(s, off, 64);
  float scale = 1.0f / fmaxf(sqrtf(s), 1e-8f);

  union { unsigned short u[4]; uint2 v; } p0, p1;
  p0.u[0] = f2bf(x0.x * scale); p0.u[1] = f2bf(x0.y * scale);
  p0.u[2] = f2bf(x0.z * scale); p0.u[3] = f2bf(x0.w * scale);
  p1.u[0] = f2bf(x1.x * scale); p1.u[1] = f2bf(x1.y * scale);
  p1.u[2] = f2bf(x1.z * scale); p1.u[3] = f2bf(x1.w * scale);
  *(uint2*)(dst + lane * 4) = p0.v;
  *(uint2*)(dst + 256 + lane * 4) = p1.v;
}

// Convert 8 fp32 (2 float4) -> 8 bf16, accumulate ssq into rs, ds_write_b128.
#define STAGE_A(xa, xb, dst)                                                   \
  do {                                                                         \
    rs += (xa).x * (xa).x + (xa).y * (xa).y + (xa).z * (xa).z +                \
          (xa).w * (xa).w + (xb).x * (xb).x + (xb).y * (xb).y +                \
          (xb).z * (xb).z + (xb).w * (xb).w;                                   \
    union { unsigned short u[8]; uint4 v; } pk;                                \
    pk.u[0] = f2bf((xa).x); pk.u[1] = f2bf((xa).y);                            \
    pk.u[2] = f2bf((xa).z); pk.u[3] = f2bf((xa).w);                            \
    pk.u[4] = f2bf((xb).x); pk.u[5] = f2bf((xb).y);                            \
    pk.u[6] = f2bf((xb).z); pk.u[7] = f2bf((xb).w);                            \
    *(uint4*)(dst) = pk.v;                                                     \
  } while (0)

// 8 MFMA over A-parity pa, B-buffer pb (2 k16 slices of the 32-col substep).
#define MFMA_PHASE(pa, pb)                                                     \
  do {                                                                         \
    __builtin_amdgcn_s_setprio(1);                                             \
    _Pragma("unroll")                                                          \
    for (int ks = 0; ks < 2; ++ks) {                                           \
      const int uo = (((ks << 1) | kh) ^ fsw) * 8;                             \
      short8 a0 = *(const short8*)&As[pa][(wm + fm) * KSUB + uo];              \
      short8 a1 = *(const short8*)&As[pa][(wm + 32 + fm) * KSUB + uo];         \
      short8 b0 = *(const short8*)&Bs[pb][(wn + fm) * KSUB + uo];              \
      short8 b1 = *(const short8*)&Bs[pb][(wn + 32 + fm) * KSUB + uo];         \
      acc[0][0] = __builtin_amdgcn_mfma_f32_32x32x16_bf16(a0, b0, acc[0][0], 0, 0, 0); \
      acc[0][1] = __builtin_amdgcn_mfma_f32_32x32x16_bf16(a0, b1, acc[0][1], 0, 0, 0); \
      acc[1][0] = __builtin_amdgcn_mfma_f32_32x32x16_bf16(a1, b0, acc[1][0], 0, 0, 0); \
      acc[1][1] = __builtin_amdgcn_mfma_f32_32x32x16_bf16(a1, b1, acc[1][1], 0, 0, 0); \
    }                                                                          \
    __builtin_amdgcn_s_setprio(0);                                             \
  } while (0)

// Raw barrier with counted vmcnt: keeps newer prefetches in flight.
#define PIPE_BARRIER(N)                                                        \
  do {                                                                         \
    asm volatile("s_waitcnt vmcnt(" #N ") lgkmcnt(0)" ::: "memory");           \
    __builtin_amdgcn_sched_barrier(0);                                         \
    __builtin_amdgcn_s_barrier();                                              \
    __builtin_amdgcn_sched_barrier(0);                                         \
  } while (0)

// Fused: C = bf16(Z) * B^T, rows scaled by 1/max(||Z_row||, 1e-8).
// Z: [M][512] fp32, B: [Npad][512] bf16 bits, C: [M][Ncls] f32.
__global__ __launch_bounds__(512, 4) void gemm_fused_kernel(
    const float* __restrict__ Z,
    const unsigned short* __restrict__ B,
    float* __restrict__ C, int M, int Ncls) {
  __shared__ unsigned short As[2][128 * KSUB];   // 2 x 8 KB
  __shared__ unsigned short Bs[3][256 * KSUB];   // 3 x 16 KB (total: 64 KB)
  // Row-norm buffer aliases As[0] after the K-loop (As[0] reads end at the
  // s=14 barrier; writes here happen only after MFMA_PHASE(15)).
  float* const ns = (float*)&As[0][0];

  const int tid = threadIdx.x;
  const int wave = tid >> 6;
  const int lane = tid & 63;

  // XCD-chunked bijective swizzle (nwg % 8 == 0).
  const int nwg = gridDim.x;
  const int cpx = nwg >> 3;
  const int bid = blockIdx.x;
  const int wg = (bid & 7) * cpx + (bid >> 3);
  const int m0 = (wg >> 2) * 128;
  const int n0 = (wg & 3) * 256;

  const int wm = (wave & 1) * 64;   // wave's M offset
  const int wn = (wave >> 1) * 64;  // wave's N offset (0..192)

  // ---- A staging map: thread t -> row t>>2, LDS slot t&3; source unit
  // pre-swizzled so LDS[r][u'] holds source unit u' ^ ((r>>1)&3).
  const int rA = tid >> 2;                 // 0..127
  const int gA = tid & 3;                  // LDS unit slot
  const int uA = gA ^ ((rA >> 1) & 3);     // source col-group
  const float* Ag = Z + (size_t)(m0 + rA) * KDIM + uA * 8;
  unsigned short* const Aw0 = &As[0][rA * KSUB + gA * 8];
  unsigned short* const Aw1 = &As[1][rA * KSUB + gA * 8];

  // ---- B staging map: per wave 2 chunks of 16 rows x 32 cols (1 KB each);
  // gl_lds writes linearly (base + lane*16); source carries the same swizzle.
  const int l2 = lane >> 2;                // row within chunk 0..15
  const int uB = (lane & 3) ^ ((l2 >> 1) & 3);
  const int c0 = wave * 2;
  const unsigned short* const Bg0 = B + (size_t)(n0 + c0 * 16 + l2) * KDIM + uB * 8;
  const unsigned short* const Bg1 = B + (size_t)(n0 + (c0 + 1) * 16 + l2) * KDIM + uB * 8;

  const int fm = lane & 31;        // fragment row (A: m, B: n)
  const int kh = lane >> 5;        // k-half
  const int fsw = (fm >> 1) & 3;   // read-side swizzle phase

  f32x16 acc[2][2] = {};
  float rs = 0.0f;                 // this thread's partial row ssq

  float4 p0a, p0b, p1a, p1b;       // A register prefetch pairs

  // ---- prologue: B(0),B(1) in flight; A(0) staged; A(1) in regs.
  p0a = *(const float4*)(Ag);
  p0b = *(const float4*)(Ag + 4);
  gload_lds16(Bg0, &Bs[0][(c0 + 0) * 16 * KSUB]);
  gload_lds16(Bg1, &Bs[0][(c0 + 1) * 16 * KSUB]);
  __builtin_amdgcn_sched_barrier(0);   // pin group boundary for vmcnt count
  p1a = *(const float4*)(Ag + KSUB);
  p1b = *(const float4*)(Ag + KSUB + 4);
  gload_lds16(Bg0 + KSUB, &Bs[1][(c0 + 0) * 16 * KSUB]);
  gload_lds16(Bg1 + KSUB, &Bs[1][(c0 + 1) * 16 * KSUB]);
  STAGE_A(p0a, p0b, Aw0);          // compiler waits A(0) regs here
  PIPE_BARRIER(4);                 // drain B(0); A(1)+B(1) stay in flight

#pragma unroll
  for (int s = 0; s < NSUB; ++s) {
    // Issue substep s+2 (B into buffer (s+2)%3, A into reg pair s&1).
    if (s + 2 < NSUB) {
      const int b2 = (s + 2) % 3;
      if ((s & 1) == 0) {
        p0a = *(const float4*)(Ag + (s + 2) * KSUB);
        p0b = *(const float4*)(Ag + (s + 2) * KSUB + 4);
      } else {
        p1a = *(const float4*)(Ag + (s + 2) * KSUB);
        p1b = *(const float4*)(Ag + (s + 2) * KSUB + 4);
      }
      gload_lds16(Bg0 + (s + 2) * KSUB, &Bs[b2][(c0 + 0) * 16 * KSUB]);
      gload_lds16(Bg1 + (s + 2) * KSUB, &Bs[b2][(c0 + 1) * 16 * KSUB]);
    }
    // Stage A(s+1): convert regs -> LDS parity (s+1)&1.
    if (s + 1 < NSUB) {
      if (((s + 1) & 1) == 0) STAGE_A(p0a, p0b, Aw0);
      else                    STAGE_A(p1a, p1b, Aw1);
    }
    // Compute substep s.
    MFMA_PHASE(s & 1, s % 3);
    // Barrier: drain B(s+1) (oldest); keep {A(s+2),B(s+2)} in flight.
    if (s + 1 < NSUB) {
      if (s + 2 < NSUB) PIPE_BARRIER(4);
      else              PIPE_BARRIER(0);
    }
  }

  // Finish row norms: 4 threads share each row (disjoint col-groups).
  // As[0] is dead (last read completed at the s=14 barrier) -> reuse as ns.
#pragma unroll
  for (int off = 1; off < 4; off <<= 1) rs += __shfl_xor(rs, off, 64);
  if ((lane & 3) == 0) ns[rA] = rs;
  __syncthreads();

  // Epilogue: C = acc * 1/max(||z_row||, eps).
  // C/D layout (32x32): col = lane&31, row = (r&3) + 8*(r>>2) + 4*(lane>>5).
  const int cn = lane & 31;
  const int ch4 = kh * 4;
#pragma unroll
  for (int mi = 0; mi < 2; ++mi) {
    float rn[16];
#pragma unroll
    for (int q = 0; q < 4; ++q) {
      float4 n4 = *(const float4*)&ns[wm + mi * 32 + q * 8 + ch4];
      rn[q * 4 + 0] = 1.0f / fmaxf(sqrtf(n4.x), 1e-8f);
      rn[q * 4 + 1] = 1.0f / fmaxf(sqrtf(n4.y), 1e-8f);
      rn[q * 4 + 2] = 1.0f / fmaxf(sqrtf(n4.z), 1e-8f);
      rn[q * 4 + 3] = 1.0f / fmaxf(sqrtf(n4.w), 1e-8f);
    }
#pragma unroll
    for (int ni = 0; ni < 2; ++ni) {
      int n = n0 + wn + ni * 32 + cn;
      if (n < Ncls) {
        size_t base = (size_t)(m0 + wm + mi * 32 + ch4) * (size_t)Ncls + n;
#pragma unroll
        for (int r = 0; r < 16; ++r) {
          int row = (r & 3) + 8 * (r >> 2);
          C[base + (size_t)row * Ncls] = acc[mi][ni][r] * rn[r];
        }
      }
    }
  }
}

extern "C" void kernel_launch(void* const* d_in, const int* in_sizes, int n_in,
                              void* d_out, int out_size, void* d_ws, size_t ws_size,
                              hipStream_t stream) {
  const float* z  = (const float*)d_in[0];
  const float* cm = (const float*)d_in[1];
  float* out = (float*)d_out;

  const int M    = in_sizes[0] / KDIM;                 // 32768
  const int Ncls = in_sizes[1] / KDIM;                 // 1001
  const int Npad = ((Ncls + 255) / 256) * 256;         // 1024

  unsigned short* bn = (unsigned short*)d_ws;          // 1 MB

  normalize_cm_kernel<<<Npad / 4, 256, 0, stream>>>(cm, bn, Ncls, Npad);

  // 1-D grid, XCD swizzle done in-kernel: (M/128) M-tiles x (Npad/256) N-tiles
  const int nwg = (M / 128) * (Npad / 256);            // 1024, % 8 == 0
  gemm_fused_kernel<<<dim3(nwg), 512, 0, stream>>>(z, bn, out, M, Ncls);
}